// Round 8
// baseline (238.353 us; speedup 1.0000x reference)
//
#include <hip/hip_runtime.h>
#include <hip/hip_bf16.h>
#include <stdint.h>

using u16 = unsigned short;
using bf16x8 = __attribute__((ext_vector_type(8))) short;
using bf16x4 = __attribute__((ext_vector_type(4))) short;
using f32x4  = __attribute__((ext_vector_type(4))) float;

__device__ __forceinline__ u16 f2bf(float f) {
  union { float f; uint32_t u; } v; v.f = f;
  uint32_t u = v.u;
  u += 0x7fffu + ((u >> 16) & 1u);
  return (u16)(u >> 16);
}

#define GLOBAL_LOAD_LDS16(gp, lp) \
  __builtin_amdgcn_global_load_lds((const __attribute__((address_space(1))) unsigned int*)(gp), \
                                   (__attribute__((address_space(3))) unsigned int*)(lp), 16, 0, 0)

#define MFMA32(a, b, c) __builtin_amdgcn_mfma_f32_16x16x32_bf16(a, b, c, 0, 0, 0)
#define MFMA16(a, b, c) __builtin_amdgcn_mfma_f32_16x16x16bf16_1k(a, b, c, 0, 0, 0)

// ---------------- merged input prep: casts (blk<8192) + weight transposes ----------------
__global__ __launch_bounds__(256) void prep_k(const float4* __restrict__ q, u16* __restrict__ q16,
                                              const float4* __restrict__ kv, u16* __restrict__ kv16,
                                              const float* __restrict__ Wq,
                                              const float* __restrict__ Wkv,
                                              const float* __restrict__ Wout,
                                              u16* __restrict__ WqT, u16* __restrict__ WkvT,
                                              u16* __restrict__ WoutT, float qscale) {
  __shared__ float tile[32][33];
  int blk = blockIdx.x;
  if (blk < 8192) {  // cast path
    const float4* in; u16* out; int i;
    if (blk < 4096) { in = q; out = q16; i = blk * 256 + threadIdx.x; }
    else { in = kv; out = kv16; i = (blk - 4096) * 256 + threadIdx.x; }
    float4 f = in[i];
    ushort4 o;
    o.x = f2bf(f.x); o.y = f2bf(f.y); o.z = f2bf(f.z); o.w = f2bf(f.w);
    *(ushort4*)(out + (size_t)i * 4) = o;
    return;
  }
  // transpose path
  int b2 = blk - 8192;
  const float* in; u16* out; float sc; int idx;
  if (b2 < 1024)      { in = Wq;   out = WqT;   sc = qscale; idx = b2; }
  else if (b2 < 3072) { in = Wkv;  out = WkvT;  sc = 1.0f;   idx = b2 - 1024; }
  else                 { in = Wout; out = WoutT; sc = 1.0f;   idx = b2 - 3072; }
  const int K = 1024;
  const int N = (b2 >= 1024 && b2 < 3072) ? 2048 : 1024;
  int bk = (idx & 31) * 32, bn = (idx >> 5) * 32;
  int tx = threadIdx.x & 31, ty = threadIdx.x >> 5;
#pragma unroll
  for (int i = 0; i < 4; i++) {
    int r = ty * 4 + i;
    tile[r][tx] = in[(size_t)(bk + r) * N + bn + tx];
  }
  __syncthreads();
#pragma unroll
  for (int i = 0; i < 4; i++) {
    int r = ty * 4 + i;
    out[(size_t)(bn + r) * K + bk + tx] = f2bf(tile[tx][r] * sc);
  }
}

// ---------------- shared GEMM body, DMA double-buffer, ONE barrier per K-iter ----------
// lA: 2*BM*32 u16, lB: 2*128*32 u16.
template <int BM, bool OUT_F32>
__device__ __forceinline__ void gemm_body(u16* lA, u16* lB,
                                          const u16* __restrict__ A, const u16* __restrict__ BT,
                                          void* __restrict__ Cv, int N, int K, int bm, int bn) {
  const int tid = threadIdx.x;
  const int lane = tid & 63, wave = tid >> 6;
  const int l15 = lane & 15, quad = lane >> 4;
  constexpr int MI = BM / 32;
  const int wm = (wave >> 1) * (BM / 2), wn = (wave & 1) * 64;

  f32x4 acc[MI][4] = {};

  const int r0 = tid >> 2, c8 = (tid & 3) * 8;
  const u16* Ab = A + (size_t)bm * BM * K + (size_t)r0 * K + c8;
  const u16* Bb = BT + (size_t)bn * 128 * K + (size_t)r0 * K + c8;

#define STAGE_G(sel, k0)                                                        \
  {                                                                             \
    u16* lAw = lA + (sel) * (BM * 32) + wave * 512;                             \
    u16* lBw = lB + (sel) * (128 * 32) + wave * 512;                            \
    _Pragma("unroll")                                                           \
    for (int t = 0; t < BM / 64; t++)                                           \
      GLOBAL_LOAD_LDS16(Ab + (k0) + (size_t)(t * 64) * K, lAw + t * 2048);      \
    _Pragma("unroll")                                                           \
    for (int t = 0; t < 2; t++)                                                 \
      GLOBAL_LOAD_LDS16(Bb + (k0) + (size_t)(t * 64) * K, lBw + t * 2048);      \
  }

  STAGE_G(0, 0);
  const int iters = K >> 5;
  for (int it = 0; it < iters; it++) {
    const int cur = it & 1;
    __syncthreads();   // vmcnt(0) drain: buf[cur] ready; readers of buf[cur^1] done
    if (it + 1 < iters) STAGE_G(cur ^ 1, (it + 1) * 32);

    const u16* lAc = lA + cur * (BM * 32);
    const u16* lBc = lB + cur * (128 * 32);
    bf16x8 aF[MI], bF[4];
#pragma unroll
    for (int mi = 0; mi < MI; mi++)
      aF[mi] = *(const bf16x8*)&lAc[(wm + mi * 16 + l15) * 32 + quad * 8];
#pragma unroll
    for (int ni = 0; ni < 4; ni++)
      bF[ni] = *(const bf16x8*)&lBc[(wn + ni * 16 + l15) * 32 + quad * 8];
#pragma unroll
    for (int mi = 0; mi < MI; mi++)
#pragma unroll
      for (int ni = 0; ni < 4; ni++)
        acc[mi][ni] = MFMA32(aF[mi], bF[ni], acc[mi][ni]);
  }
#undef STAGE_G

  const int col0 = bn * 128 + wn + l15;
  const int rowb = bm * BM + wm + quad * 4;
#pragma unroll
  for (int mi = 0; mi < MI; mi++) {
#pragma unroll
    for (int ni = 0; ni < 4; ni++) {
#pragma unroll
      for (int r = 0; r < 4; r++) {
        int row = rowb + mi * 16 + r;
        int col = col0 + ni * 16;
        float v = acc[mi][ni][r];
        if (OUT_F32) ((float*)Cv)[(size_t)row * N + col] = v;
        else         ((u16*)Cv)[(size_t)row * N + col] = f2bf(v);
      }
    }
  }
}

// merged qp + kvp projection
__global__ __launch_bounds__(256) void proj_k(const u16* __restrict__ q16, const u16* __restrict__ WqT,
                                              u16* __restrict__ qp,
                                              const u16* __restrict__ kv16, const u16* __restrict__ WkvT,
                                              u16* __restrict__ kvp) {
  __shared__ u16 lA[2 * 128 * 32];
  __shared__ u16 lB[2 * 128 * 32];
  int blk = blockIdx.x;
  if (blk < 256) gemm_body<128, false>(lA, lB, q16, WqT, qp, 1024, 1024, blk >> 3, blk & 7);
  else { int b2 = blk - 256; gemm_body<128, false>(lA, lB, kv16, WkvT, kvp, 2048, 1024, b2 >> 4, b2 & 15); }
}

// output projection: 64x128 tiles -> 512 blocks
__global__ __launch_bounds__(256) void gemm_out_k(const u16* __restrict__ A, const u16* __restrict__ BT,
                                                  float* __restrict__ C) {
  __shared__ u16 lA[2 * 64 * 32];
  __shared__ u16 lB[2 * 128 * 32];
  int blk = blockIdx.x;
  gemm_body<64, true>(lA, lB, A, BT, C, 1024, 1024, blk >> 3, blk & 7);
}

// ---------------- global V transpose: kvp V-half (j,d) -> VT[b][h][d][j] ----------------
__global__ __launch_bounds__(256) void vt_k(const u16* __restrict__ kvp,
                                            u16* __restrict__ VT) {
  __shared__ u16 lT[64 * 64];
  const int jt = blockIdx.x & 31;
  const int bh = blockIdx.x >> 5;
  const int b = bh >> 4, h = bh & 15;
  const int j0 = jt * 64;
  const int u = threadIdx.x;
  const int su = u >> 3;
  const int sc = (u & 7) * 8;

#pragma unroll
  for (int t = 0; t < 2; t++) {
    int j = su + t * 32;
    int s = (j ^ (j >> 3)) & 7;
    uint4 vv = *(const uint4*)(kvp + (size_t)(b * 2048 + j0 + j) * 2048 + 1024 + h * 64 + sc);
    *(uint4*)&lT[j * 64 + (sc ^ (s << 3))] = vv;
  }
  __syncthreads();

  const int jg = u & 7;
#pragma unroll
  for (int t = 0; t < 2; t++) {
    int d = su + t * 32;
    u16 tmp[8];
#pragma unroll
    for (int i = 0; i < 8; i++) {
      int j = jg * 8 + i;
      int s = (j ^ (j >> 3)) & 7;
      tmp[i] = lT[j * 64 + (d ^ (s << 3))];
    }
    *(uint4*)(VT + ((size_t)bh * 64 + d) * 2048 + j0 + jg * 8) = *(const uint4*)tmp;
  }
}

// ---------------- flash attention: 128 Q-rows/block, S^T + register PV, LDS dbuf DMA ----
// grid: (B*H)*16 = 512 blocks = exactly 2/CU (64 KB LDS); 4 waves; j-tile=128, 16 iters.
// Each wave handles TWO 16-row Q sub-tiles (qt=0,1) -> 2x compute per staged K/V tile,
// halved staging traffic + barrier count per unit work vs 64-row version.
// sacc reused across qt to bound VGPR (~150 < the 256 budget 2-wave/SIMD implies).
__global__ __launch_bounds__(256) void flash_attn_k(const u16* __restrict__ qp,
                                                    const u16* __restrict__ kvp,
                                                    const u16* __restrict__ VT,
                                                    u16* __restrict__ attn_out) {
  const int NSEQ = 2048, D = 1024, LDKV = 2048;
  const int mtile = blockIdx.x & 15;
  const int bh = blockIdx.x >> 4;
  const int b = bh >> 4, h = bh & 15;
  const int tid = threadIdx.x;
  const int lane = tid & 63, wave = tid >> 6;
  const int quad = lane >> 4, l15 = lane & 15;

  __shared__ u16 lK[2][128 * 64];
  __shared__ u16 lV[2][64 * 128];

  const u16* Qb  = qp + (size_t)(b * NSEQ + mtile * 128) * D + h * 64;
  const u16* Kb  = kvp + (size_t)(b * NSEQ) * LDKV + h * 64;
  const u16* VTb = VT + (size_t)bh * 64 * 2048;

  bf16x8 qa[2][2];
#pragma unroll
  for (int qt = 0; qt < 2; qt++)
#pragma unroll
    for (int ks = 0; ks < 2; ks++)
      qa[qt][ks] = *(const bf16x8*)(Qb + (size_t)(qt * 64 + wave * 16 + l15) * D + ks * 32 + quad * 8);

#define STAGE(sel, J0)                                                                   \
  {                                                                                      \
    _Pragma("unroll")                                                                    \
    for (int t = 0; t < 4; t++) {                                                        \
      int g = t * 256 + tid;                                                             \
      int jr = g >> 3;                                                                   \
      int c = (g & 7) ^ (jr & 7);                                                        \
      GLOBAL_LOAD_LDS16(Kb + (size_t)((J0) + jr) * LDKV + c * 8,                         \
                        &lK[sel][wave * 512 + t * 2048]);                                \
    }                                                                                    \
    _Pragma("unroll")                                                                    \
    for (int t = 0; t < 4; t++) {                                                        \
      int g = t * 256 + tid;                                                             \
      int d = g >> 4;                                                                    \
      int c = (g & 15) ^ (d & 7);                                                        \
      GLOBAL_LOAD_LDS16(VTb + (size_t)d * 2048 + (J0) + c * 8,                           \
                        &lV[sel][wave * 512 + t * 2048]);                                \
    }                                                                                    \
  }

  STAGE(0, 0);

  f32x4 oacc[2][4] = {};
  float rs2[2] = {0.f, 0.f};

  for (int it = 0; it < 16; it++) {
    const int cur = it & 1;
    __syncthreads();   // vmcnt(0) drain: tile it ready; readers of buf cur^1 done
    if (it < 15) STAGE(cur ^ 1, (it + 1) * 128);

    const u16* lKc = lK[cur];
    const u16* lVc = lV[cur];
#pragma unroll
    for (int qt = 0; qt < 2; qt++) {
      // S^T = K*Q^T : A = K rows (m=key), B = Q rows (n=query); exp2-domain logits
      f32x4 sacc[8] = {};
#pragma unroll
      for (int ks = 0; ks < 2; ks++)
#pragma unroll
        for (int ni = 0; ni < 8; ni++) {
          int p = ((ks * 4 + quad) ^ (l15 & 7)) * 8;
          bf16x8 kb = *(const bf16x8*)&lKc[(ni * 16 + l15) * 64 + p];
          sacc[ni] = MFMA32(kb, qa[qt][ks], sacc[ni]);
        }

      float rs = 0.f;
#pragma unroll
      for (int ni = 0; ni < 8; ni++) {
        float p0 = __builtin_amdgcn_exp2f(sacc[ni][0]);
        float p1 = __builtin_amdgcn_exp2f(sacc[ni][1]);
        float p2 = __builtin_amdgcn_exp2f(sacc[ni][2]);
        float p3 = __builtin_amdgcn_exp2f(sacc[ni][3]);
        rs += (p0 + p1) + (p2 + p3);
        union { uint32_t u[2]; bf16x4 v; } pa;
        __hip_bfloat162 w01 = __float22bfloat162_rn(float2{p0, p1});
        __hip_bfloat162 w23 = __float22bfloat162_rn(float2{p2, p3});
        pa.u[0] = *(uint32_t*)&w01;
        pa.u[1] = *(uint32_t*)&w23;
#pragma unroll
        for (int di = 0; di < 4; di++) {
          int p = (((2 * ni + (quad >> 1)) ^ (l15 & 7)) * 8) + (quad & 1) * 4;
          bf16x4 vb = *(const bf16x4*)&lVc[(di * 16 + l15) * 128 + p];
          oacc[qt][di] = MFMA16(pa.v, vb, oacc[qt][di]);
        }
      }
      rs2[qt] += rs;
    }
  }

  u16* Ob = attn_out + (size_t)(b * NSEQ + mtile * 128) * D + h * 64;
#pragma unroll
  for (int qt = 0; qt < 2; qt++) {
    float rs = rs2[qt];
    rs += __shfl_xor(rs, 16, 64);
    rs += __shfl_xor(rs, 32, 64);
    float inv = 1.0f / rs;             // valid per lane for query = l15
    float invq[4];
#pragma unroll
    for (int r = 0; r < 4; r++)
      invq[r] = __shfl(inv, (lane & 48) + ((lane >> 4) << 2) + r, 64);
#pragma unroll
    for (int di = 0; di < 4; di++)
#pragma unroll
      for (int r = 0; r < 4; r++) {
        float v = oacc[qt][di][r] * invq[r];
        Ob[(size_t)(qt * 64 + wave * 16 + quad * 4 + r) * D + di * 16 + l15] = f2bf(v);
      }
  }
}

extern "C" void kernel_launch(void* const* d_in, const int* in_sizes, int n_in,
                              void* d_out, int out_size, void* d_ws, size_t ws_size,
                              hipStream_t stream) {
  const float* q    = (const float*)d_in[0];
  const float* kv   = (const float*)d_in[1];
  const float* Wq   = (const float*)d_in[2];
  const float* Wkv  = (const float*)d_in[3];
  const float* Wout = (const float*)d_in[4];
  float* out = (float*)d_out;

  char* ws = (char*)d_ws;
  const size_t MB = 1024 * 1024;
  u16* q16   = (u16*)(ws + 0);        // 8MB; reused as attn_out after proj
  u16* kv16  = (u16*)(ws + 8 * MB);   // 8MB; reused as VT after proj
  u16* WqT   = (u16*)(ws + 16 * MB);  // 2MB
  u16* WkvT  = (u16*)(ws + 18 * MB);  // 4MB
  u16* WoutT = (u16*)(ws + 22 * MB);  // 2MB
  u16* qp    = (u16*)(ws + 24 * MB);  // 8MB
  u16* kvp   = (u16*)(ws + 32 * MB);  // 16MB
  u16* attn  = q16;
  u16* VT    = kv16;

  const float qscale = 0.125f * 1.44269504f;  // softmax scale * log2(e)

  prep_k<<<12288, 256, 0, stream>>>((const float4*)q, q16, (const float4*)kv, kv16,
                                    Wq, Wkv, Wout, WqT, WkvT, WoutT, qscale);
  proj_k<<<768, 256, 0, stream>>>(q16, WqT, qp, kv16, WkvT, kvp);
  vt_k<<<1024, 256, 0, stream>>>(kvp, VT);
  flash_attn_k<<<512, 256, 0, stream>>>(qp, kvp, VT, attn);
  gemm_out_k<<<512, 256, 0, stream>>>(attn, WoutT, out);
}

// Round 9
// 221.296 us; speedup vs baseline: 1.0771x; 1.0771x over previous
//
#include <hip/hip_runtime.h>
#include <hip/hip_bf16.h>
#include <stdint.h>

using u16 = unsigned short;
using bf16x8 = __attribute__((ext_vector_type(8))) short;
using bf16x4 = __attribute__((ext_vector_type(4))) short;
using f32x4  = __attribute__((ext_vector_type(4))) float;

__device__ __forceinline__ u16 f2bf(float f) {
  union { float f; uint32_t u; } v; v.f = f;
  uint32_t u = v.u;
  u += 0x7fffu + ((u >> 16) & 1u);
  return (u16)(u >> 16);
}

#define GLOBAL_LOAD_LDS16(gp, lp) \
  __builtin_amdgcn_global_load_lds((const __attribute__((address_space(1))) unsigned int*)(gp), \
                                   (__attribute__((address_space(3))) unsigned int*)(lp), 16, 0, 0)

#define MFMA32(a, b, c) __builtin_amdgcn_mfma_f32_16x16x32_bf16(a, b, c, 0, 0, 0)
#define MFMA16(a, b, c) __builtin_amdgcn_mfma_f32_16x16x16bf16_1k(a, b, c, 0, 0, 0)

// ---------------- merged input prep: casts (blk<8192) + weight transposes ----------------
__global__ __launch_bounds__(256) void prep_k(const float4* __restrict__ q, u16* __restrict__ q16,
                                              const float4* __restrict__ kv, u16* __restrict__ kv16,
                                              const float* __restrict__ Wq,
                                              const float* __restrict__ Wkv,
                                              const float* __restrict__ Wout,
                                              u16* __restrict__ WqT, u16* __restrict__ WkvT,
                                              u16* __restrict__ WoutT, float qscale) {
  __shared__ float tile[32][33];
  int blk = blockIdx.x;
  if (blk < 8192) {  // cast path
    const float4* in; u16* out; int i;
    if (blk < 4096) { in = q; out = q16; i = blk * 256 + threadIdx.x; }
    else { in = kv; out = kv16; i = (blk - 4096) * 256 + threadIdx.x; }
    float4 f = in[i];
    ushort4 o;
    o.x = f2bf(f.x); o.y = f2bf(f.y); o.z = f2bf(f.z); o.w = f2bf(f.w);
    *(ushort4*)(out + (size_t)i * 4) = o;
    return;
  }
  // transpose path
  int b2 = blk - 8192;
  const float* in; u16* out; float sc; int idx;
  if (b2 < 1024)      { in = Wq;   out = WqT;   sc = qscale; idx = b2; }
  else if (b2 < 3072) { in = Wkv;  out = WkvT;  sc = 1.0f;   idx = b2 - 1024; }
  else                 { in = Wout; out = WoutT; sc = 1.0f;   idx = b2 - 3072; }
  const int K = 1024;
  const int N = (b2 >= 1024 && b2 < 3072) ? 2048 : 1024;
  int bk = (idx & 31) * 32, bn = (idx >> 5) * 32;
  int tx = threadIdx.x & 31, ty = threadIdx.x >> 5;
#pragma unroll
  for (int i = 0; i < 4; i++) {
    int r = ty * 4 + i;
    tile[r][tx] = in[(size_t)(bk + r) * N + bn + tx];
  }
  __syncthreads();
#pragma unroll
  for (int i = 0; i < 4; i++) {
    int r = ty * 4 + i;
    out[(size_t)(bn + r) * K + bk + tx] = f2bf(tile[tx][r] * sc);
  }
}

// ---------------- shared GEMM body (R7 form: single-buffer, 2 barriers/iter) ----------
template <int BM, bool OUT_F32>
__device__ __forceinline__ void gemm_body(u16* lA, u16* lB,
                                          const u16* __restrict__ A, const u16* __restrict__ BT,
                                          void* __restrict__ Cv, int N, int K, int bm, int bn) {
  const int tid = threadIdx.x;
  const int lane = tid & 63, wave = tid >> 6;
  const int l15 = lane & 15, quad = lane >> 4;
  constexpr int MI = BM / 32;
  const int wm = (wave >> 1) * (BM / 2), wn = (wave & 1) * 64;

  f32x4 acc[MI][4] = {};

  const u16* Abase = A + (size_t)bm * BM * K;
  const u16* Bbase = BT + (size_t)bn * 128 * K;
  const int r0 = tid >> 2, c8 = (tid & 3) * 8;

  u16* lAw = lA + wave * 512;
  u16* lBw = lB + wave * 512;

  for (int k0 = 0; k0 < K; k0 += 32) {
    const u16* Ag = Abase + k0 + (size_t)r0 * K + c8;
    const u16* Bg = Bbase + k0 + (size_t)r0 * K + c8;
#pragma unroll
    for (int t = 0; t < BM / 64; t++)
      GLOBAL_LOAD_LDS16(Ag + (size_t)(t * 64) * K, lAw + t * 2048);
#pragma unroll
    for (int t = 0; t < 2; t++)
      GLOBAL_LOAD_LDS16(Bg + (size_t)(t * 64) * K, lBw + t * 2048);
    __syncthreads();

    bf16x8 aF[MI], bF[4];
#pragma unroll
    for (int mi = 0; mi < MI; mi++)
      aF[mi] = *(const bf16x8*)&lA[(wm + mi * 16 + l15) * 32 + quad * 8];
#pragma unroll
    for (int ni = 0; ni < 4; ni++)
      bF[ni] = *(const bf16x8*)&lB[(wn + ni * 16 + l15) * 32 + quad * 8];
#pragma unroll
    for (int mi = 0; mi < MI; mi++)
#pragma unroll
      for (int ni = 0; ni < 4; ni++)
        acc[mi][ni] = MFMA32(aF[mi], bF[ni], acc[mi][ni]);
    __syncthreads();
  }

  const int col0 = bn * 128 + wn + l15;
  const int rowb = bm * BM + wm + quad * 4;
#pragma unroll
  for (int mi = 0; mi < MI; mi++) {
#pragma unroll
    for (int ni = 0; ni < 4; ni++) {
#pragma unroll
      for (int r = 0; r < 4; r++) {
        int row = rowb + mi * 16 + r;
        int col = col0 + ni * 16;
        float v = acc[mi][ni][r];
        if (OUT_F32) ((float*)Cv)[(size_t)row * N + col] = v;
        else         ((u16*)Cv)[(size_t)row * N + col] = f2bf(v);
      }
    }
  }
}

// merged qp + kvp projection
__global__ __launch_bounds__(256) void proj_k(const u16* __restrict__ q16, const u16* __restrict__ WqT,
                                              u16* __restrict__ qp,
                                              const u16* __restrict__ kv16, const u16* __restrict__ WkvT,
                                              u16* __restrict__ kvp) {
  __shared__ u16 lA[128 * 32];
  __shared__ u16 lB[128 * 32];
  int blk = blockIdx.x;
  if (blk < 256) gemm_body<128, false>(lA, lB, q16, WqT, qp, 1024, 1024, blk >> 3, blk & 7);
  else { int b2 = blk - 256; gemm_body<128, false>(lA, lB, kv16, WkvT, kvp, 2048, 1024, b2 >> 4, b2 & 15); }
}

// output projection: 64x128 tiles -> 512 blocks
__global__ __launch_bounds__(256) void gemm_out_k(const u16* __restrict__ A, const u16* __restrict__ BT,
                                                  float* __restrict__ C) {
  __shared__ u16 lA[64 * 32];
  __shared__ u16 lB[128 * 32];
  int blk = blockIdx.x;
  gemm_body<64, true>(lA, lB, A, BT, C, 1024, 1024, blk >> 3, blk & 7);
}

// ---------------- global V transpose: kvp V-half (j,d) -> VT[b][h][d][j] ----------------
__global__ __launch_bounds__(256) void vt_k(const u16* __restrict__ kvp,
                                            u16* __restrict__ VT) {
  __shared__ u16 lT[64 * 64];
  const int jt = blockIdx.x & 31;
  const int bh = blockIdx.x >> 5;
  const int b = bh >> 4, h = bh & 15;
  const int j0 = jt * 64;
  const int u = threadIdx.x;
  const int su = u >> 3;
  const int sc = (u & 7) * 8;

#pragma unroll
  for (int t = 0; t < 2; t++) {
    int j = su + t * 32;
    int s = (j ^ (j >> 3)) & 7;
    uint4 vv = *(const uint4*)(kvp + (size_t)(b * 2048 + j0 + j) * 2048 + 1024 + h * 64 + sc);
    *(uint4*)&lT[j * 64 + (sc ^ (s << 3))] = vv;
  }
  __syncthreads();

  const int jg = u & 7;
#pragma unroll
  for (int t = 0; t < 2; t++) {
    int d = su + t * 32;
    u16 tmp[8];
#pragma unroll
    for (int i = 0; i < 8; i++) {
      int j = jg * 8 + i;
      int s = (j ^ (j >> 3)) & 7;
      tmp[i] = lT[j * 64 + (d ^ (s << 3))];
    }
    *(uint4*)(VT + ((size_t)bh * 64 + d) * 2048 + j0 + jg * 8) = *(const uint4*)tmp;
  }
}

// ---------------- flash attention: 2x2 wave split (kw x qw), register PV, LDS dbuf DMA ----
// grid: (B*H)*32 = 1024 blocks; 4 waves; 64 Q rows/block; j-tile=128, 16 iters.
// Wave (kw=wave&1, qw=wave>>1): keys kw*64..+63, queries qw*32..+31 (2 nq groups).
// Each wave reads HALF the K tile and HALF the V rows -> 16 KB LDS reads/wave/iter
// (was 32 KB = every wave reading everything). kb (8 b128) and vb (16 b64) hoisted.
// Fixed-max softmax makes the key split associative: partial O / row-sums combined
// once at the end via LDS (kw=1 writes, barrier, kw=0 adds + stores).
__global__ __launch_bounds__(256) void flash_attn_k(const u16* __restrict__ qp,
                                                    const u16* __restrict__ kvp,
                                                    const u16* __restrict__ VT,
                                                    u16* __restrict__ attn_out) {
  const int NSEQ = 2048, D = 1024, LDKV = 2048;
  const int mtile = blockIdx.x & 31;
  const int bh = blockIdx.x >> 5;
  const int b = bh >> 4, h = bh & 15;
  const int tid = threadIdx.x;
  const int lane = tid & 63, wave = tid >> 6;
  const int quad = lane >> 4, l15 = lane & 15;
  const int kw = wave & 1, qw = wave >> 1;

  __shared__ u16 lK[2][128 * 64];   // row j: 8 chunks of 16B at pos c ^ (j&7)
  __shared__ u16 lV[2][64 * 128];   // row d: 16 chunks of 16B at pos c ^ (d&7)

  const u16* Qb  = qp + (size_t)(b * NSEQ + mtile * 64) * D + h * 64;
  const u16* Kb  = kvp + (size_t)(b * NSEQ) * LDKV + h * 64;
  const u16* VTb = VT + (size_t)bh * 64 * 2048;

  // Q fragments: queries qw*32 + nq*16 + l15
  bf16x8 qa[2][2];
#pragma unroll
  for (int nq = 0; nq < 2; nq++)
#pragma unroll
    for (int ks = 0; ks < 2; ks++)
      qa[nq][ks] = *(const bf16x8*)(Qb + (size_t)(qw * 32 + nq * 16 + l15) * D + ks * 32 + quad * 8);

#define STAGE(sel, J0)                                                                   \
  {                                                                                      \
    _Pragma("unroll")                                                                    \
    for (int t = 0; t < 4; t++) {                                                        \
      int g = t * 256 + tid;                                                             \
      int jr = g >> 3;                                                                   \
      int c = (g & 7) ^ (jr & 7);                                                        \
      GLOBAL_LOAD_LDS16(Kb + (size_t)((J0) + jr) * LDKV + c * 8,                         \
                        &lK[sel][wave * 512 + t * 2048]);                                \
    }                                                                                    \
    _Pragma("unroll")                                                                    \
    for (int t = 0; t < 4; t++) {                                                        \
      int g = t * 256 + tid;                                                             \
      int d = g >> 4;                                                                    \
      int c = (g & 15) ^ (d & 7);                                                        \
      GLOBAL_LOAD_LDS16(VTb + (size_t)d * 2048 + (J0) + c * 8,                           \
                        &lV[sel][wave * 512 + t * 2048]);                                \
    }                                                                                    \
  }

  STAGE(0, 0);

  f32x4 oacc[2][4] = {};     // [nq][di], queries = rows quad*4+r, d = di*16+l15
  float rs[2] = {0.f, 0.f};  // per-lane partials, query = l15 (per nq)

  for (int it = 0; it < 16; it++) {
    const int cur = it & 1;
    __syncthreads();   // vmcnt(0) drain: tile it ready; readers of buf cur^1 done
    if (it < 15) STAGE(cur ^ 1, (it + 1) * 128);

    const u16* lKc = lK[cur];
    const u16* lVc = lV[cur];

    // hoisted K fragments: keys kw*64 + ni*16 + l15 (j&7 == l15&7)
    bf16x8 kb[2][4];
#pragma unroll
    for (int ks = 0; ks < 2; ks++)
#pragma unroll
      for (int ni = 0; ni < 4; ni++)
        kb[ks][ni] = *(const bf16x8*)&lKc[(kw * 64 + ni * 16 + l15) * 64 +
                                          (((ks * 4 + quad) ^ (l15 & 7)) * 8)];
    // hoisted V fragments: d = di*16+l15, keys kw*64 + ni*16 + quad*4..+3
    bf16x4 vb[4][4];
#pragma unroll
    for (int ni = 0; ni < 4; ni++)
#pragma unroll
      for (int di = 0; di < 4; di++)
        vb[ni][di] = *(const bf16x4*)&lVc[(di * 16 + l15) * 128 +
                                          ((kw * 8) | ((ni * 2 + (quad >> 1)) ^ (l15 & 7))) * 8 +
                                          (quad & 1) * 4];

#pragma unroll
    for (int nq = 0; nq < 2; nq++) {
      // S^T = K*Q^T : m=key (16 per ni), n=query (16); exp2-domain logits
      f32x4 sacc[4] = {};
#pragma unroll
      for (int ks = 0; ks < 2; ks++)
#pragma unroll
        for (int ni = 0; ni < 4; ni++)
          sacc[ni] = MFMA32(kb[ks][ni], qa[nq][ks], sacc[ni]);

#pragma unroll
      for (int ni = 0; ni < 4; ni++) {
        float p0 = __builtin_amdgcn_exp2f(sacc[ni][0]);
        float p1 = __builtin_amdgcn_exp2f(sacc[ni][1]);
        float p2 = __builtin_amdgcn_exp2f(sacc[ni][2]);
        float p3 = __builtin_amdgcn_exp2f(sacc[ni][3]);
        rs[nq] += (p0 + p1) + (p2 + p3);
        union { uint32_t u[2]; bf16x4 v; } pa;
        __hip_bfloat162 w01 = __float22bfloat162_rn(float2{p0, p1});
        __hip_bfloat162 w23 = __float22bfloat162_rn(float2{p2, p3});
        pa.u[0] = *(uint32_t*)&w01;
        pa.u[1] = *(uint32_t*)&w23;
#pragma unroll
        for (int di = 0; di < 4; di++)
          oacc[nq][di] = MFMA16(pa.v, vb[ni][di], oacc[nq][di]);
      }
    }
  }

  // reduce rs over quads: every lane then holds sum over this wave's 64 keys for query l15
#pragma unroll
  for (int nq = 0; nq < 2; nq++) {
    rs[nq] += __shfl_xor(rs[nq], 16, 64);
    rs[nq] += __shfl_xor(rs[nq], 32, 64);
  }

  // cross-kw combine via LDS (lK[0] area is dead: last compute reads lK[1])
  float* cb = (float*)lK;          // 16 tiles x 256 floats = 16 KB
  float* rb = (float*)lV;          // 64 floats
  if (kw == 1) {
#pragma unroll
    for (int nq = 0; nq < 2; nq++) {
#pragma unroll
      for (int di = 0; di < 4; di++)
#pragma unroll
        for (int r = 0; r < 4; r++)
          cb[((qw * 2 + nq) * 4 + di) * 256 + (quad * 4 + r) * 16 + l15] = oacc[nq][di][r];
      if (quad == 0) rb[(qw * 2 + nq) * 16 + l15] = rs[nq];
    }
  }
  __syncthreads();
  if (kw == 0) {
    u16* Ob = attn_out + (size_t)(b * NSEQ + mtile * 64) * D + h * 64;
#pragma unroll
    for (int nq = 0; nq < 2; nq++) {
      rs[nq] += rb[(qw * 2 + nq) * 16 + l15];
      float inv = 1.0f / rs[nq];
      float invq[4];
#pragma unroll
      for (int r = 0; r < 4; r++)
        invq[r] = __shfl(inv, (lane & 48) + ((lane >> 4) << 2) + r, 64);
#pragma unroll
      for (int di = 0; di < 4; di++)
#pragma unroll
        for (int r = 0; r < 4; r++) {
          float v = (oacc[nq][di][r] +
                     cb[((qw * 2 + nq) * 4 + di) * 256 + (quad * 4 + r) * 16 + l15]) * invq[r];
          Ob[(size_t)(qw * 32 + nq * 16 + quad * 4 + r) * D + di * 16 + l15] = f2bf(v);
        }
    }
  }
}

extern "C" void kernel_launch(void* const* d_in, const int* in_sizes, int n_in,
                              void* d_out, int out_size, void* d_ws, size_t ws_size,
                              hipStream_t stream) {
  const float* q    = (const float*)d_in[0];
  const float* kv   = (const float*)d_in[1];
  const float* Wq   = (const float*)d_in[2];
  const float* Wkv  = (const float*)d_in[3];
  const float* Wout = (const float*)d_in[4];
  float* out = (float*)d_out;

  char* ws = (char*)d_ws;
  const size_t MB = 1024 * 1024;
  u16* q16   = (u16*)(ws + 0);        // 8MB; reused as attn_out after proj
  u16* kv16  = (u16*)(ws + 8 * MB);   // 8MB; reused as VT after proj
  u16* WqT   = (u16*)(ws + 16 * MB);  // 2MB
  u16* WkvT  = (u16*)(ws + 18 * MB);  // 4MB
  u16* WoutT = (u16*)(ws + 22 * MB);  // 2MB
  u16* qp    = (u16*)(ws + 24 * MB);  // 8MB
  u16* kvp   = (u16*)(ws + 32 * MB);  // 16MB
  u16* attn  = q16;
  u16* VT    = kv16;

  const float qscale = 0.125f * 1.44269504f;  // softmax scale * log2(e)

  prep_k<<<12288, 256, 0, stream>>>((const float4*)q, q16, (const float4*)kv, kv16,
                                    Wq, Wkv, Wout, WqT, WkvT, WoutT, qscale);
  proj_k<<<768, 256, 0, stream>>>(q16, WqT, qp, kv16, WkvT, kvp);
  vt_k<<<1024, 256, 0, stream>>>(kvp, VT);
  flash_attn_k<<<1024, 256, 0, stream>>>(qp, kvp, VT, attn);
  gemm_out_k<<<512, 256, 0, stream>>>(attn, WoutT, out);
}